// Round 13
// baseline (1706.124 us; speedup 1.0000x reference)
//
#include <hip/hip_runtime.h>
#include <cstdint>

// ---------------- problem constants ----------------
#define NPOS 8192              // 8*32*32 spatial positions
#define KTOT 6912              // 27 taps * 256 channels
#define XP_ROWS 11560          // 10*34*34 padded spatial rows
#define XP_SY 34
#define XP_SZ 1156             // 34*34
#define KS 4                   // K-splits
#define KSL 1728               // KTOT/KS
#define NCHUNK 27              // KSL/64

typedef float  facc_t __attribute__((ext_vector_type(4)));
typedef short  bf8_t  __attribute__((ext_vector_type(8)));   // MFMA bf16 frag (4 VGPRs)
typedef unsigned short ub8_t __attribute__((ext_vector_type(8)));

__device__ __forceinline__ unsigned short f2bf(float f) {
    unsigned u = __float_as_uint(f);
    u = (u + 0x7FFFu + ((u >> 16) & 1u)) >> 16;   // RNE
    return (unsigned short)u;
}
__device__ __forceinline__ float bf2f(unsigned short u) {
    return __uint_as_float(((unsigned)u) << 16);
}

// ---------------- zero XpA+XpB (adjacent, 2*2,959,360 us) ----------------
__global__ __launch_bounds__(256) void zero_k(unsigned short* __restrict__ dst) {
    ub8_t zz = {0,0,0,0,0,0,0,0};
    *(ub8_t*)&dst[((size_t)blockIdx.x * 256 + threadIdx.x) * 8] = zz;
}

// ---------------- pad x: fp32 c-major (256,8192) -> interior of XpA[row][256] bf16 ----------------
__global__ __launch_bounds__(256) void pad_x_t(const float* __restrict__ x,
                                               unsigned short* __restrict__ XpA) {
    __shared__ unsigned short T[256 * 33];
    int b = blockIdx.x;
    int z = b >> 5, y = b & 31;
    int t = threadIdx.x;
    int c8 = t >> 5, xv = t & 31;
#pragma unroll 4
    for (int i = 0; i < 32; ++i) {
        int c = i * 8 + c8;
        T[c * 33 + xv] = f2bf(x[c * NPOS + (z << 10) + (y << 5) + xv]);
    }
    __syncthreads();
    int rowb = ((z + 1) * XP_SZ + (y + 1) * XP_SY + 1) * 256;
#pragma unroll 4
    for (int j = 0; j < 32; ++j) {
        XpA[rowb + j * 256 + t] = T[t * 33 + j];
    }
}

// ---------------- all 8 weight transposes in one launch ----------------
__global__ __launch_bounds__(256) void wtrans_all(
    const float* __restrict__ o1, const float* __restrict__ o2,
    const float* __restrict__ o3, const float* __restrict__ o4,
    const float* __restrict__ m1, const float* __restrict__ m2,
    const float* __restrict__ m3, const float* __restrict__ m4,
    unsigned short* __restrict__ wtoff, unsigned short* __restrict__ wtmain) {
    __shared__ float T[6912];
    int b = blockIdx.x, t = threadIdx.x;
    const float* src; unsigned short* dst; int o, O;
    if (b < 512) {
        int L = b >> 7; o = b & 127; O = 108;
        src = (L == 0) ? o1 : (L == 1) ? o2 : (L == 2) ? o3 : o4;
        dst = wtoff + ((size_t)(L * 128 + o)) * KTOT;
    } else {
        int b2 = b - 512;
        int L = b2 >> 8; o = b2 & 255; O = 256;
        src = (L == 0) ? m1 : (L == 1) ? m2 : (L == 2) ? m3 : m4;
        dst = wtmain + ((size_t)(L * 256 + o)) * KTOT;
    }
    if (o < O) {
#pragma unroll 3
        for (int i = 0; i < 27; ++i) T[i * 256 + t] = src[(size_t)o * KTOT + i * 256 + t];
        __syncthreads();
#pragma unroll 3
        for (int i = 0; i < 27; ++i) {
            int kc = i * 256 + t;
            int c = kc & 255, k = kc >> 8;
            dst[kc] = f2bf(T[c * 27 + k]);
        }
    } else {
#pragma unroll 3
        for (int i = 0; i < 27; ++i) dst[i * 256 + t] = 0;
    }
}

// ---------------- fused implicit GEMM (conv or deformable), K-split partials ----------------
// R6 (T4, verified): raw s_barrier, vmcnt never drained.
// R8 (verified on conv): staging pipelined one chunk ahead in registers.
// R12: deform gather pipeline deepened to DEPTH 2 — chunk c+2's 16 gathers
// issue at chunk c, ping-ponging named register buffers stvA/stvB (rule #20:
// no runtime indexing). Per-buffer cwA/cwB capture tap weights at ISSUE time
// (blend-time cw may have advanced a tap). Issues remain strictly in chunk
// order, so the ktap/dn lookahead chain is unchanged. In-flight window grows
// from ~1 scheduling-region chain (~600cy) to ~2 full chunks — covers
// HBM-miss gather latency that depth-1 left exposed (83MB FETCH/dispatch).
template<bool DEFORM>
__global__ __launch_bounds__(256, 2)
void fgemm(const unsigned short* __restrict__ Xp,
           const unsigned short* __restrict__ wt,   // [O][KTOT] bf16
           const float* __restrict__ dbuf,          // [108][8192] (DEFORM only)
           float* __restrict__ parts) {
    constexpr int O   = DEFORM ? 256 : 128;
    constexpr int PWN = DEFORM ? 4 : 2;             // p-frags per wave
    __shared__ unsigned short Bs[64 * 64] __attribute__((aligned(16)));

    const int t = threadIdx.x;
    const int wave = t >> 6, lane = t & 63;
    const int q = lane >> 4, r = lane & 15;

    // ---- XCD-chunked swizzle (neutral R5; kept — grid (128,4)) ----
    const int bid = blockIdx.x + (blockIdx.y << 7);
    const int xcd = bid & 7;
    const int idx = bid >> 3;
    const int pt  = (xcd << 4) | (idx & 15);
    const int ks  = idx >> 4;
    const int pbase = pt * 64;
    const int kstart = ks * KSL;

    const int obw = DEFORM ? (wave * 64) : ((wave >> 1) * 64);
    const int pfb = DEFORM ? 0 : ((wave & 1) * 32);

    // staging coords: thread -> (p_local = t>>2, 16 channels at csub)
    const int pl = t >> 2;
    const int csub = (t & 3) * 16;
    const int p = pbase + pl;
    const int z = p >> 10, y = (p >> 5) & 31, xx = p & 31;
    const int g0 = (t & 3) * 2;
    const int wr0 = pl * 64 + ((g0 ^ (pl & 7)) << 3);
    const int wr1 = pl * 64 + (((g0 + 1) ^ (pl & 7)) << 3);

    facc_t acc[4][PWN];
#pragma unroll
    for (int i = 0; i < 4; ++i)
#pragma unroll
        for (int ip = 0; ip < PWN; ++ip) acc[i][ip] = (facc_t){0.f, 0.f, 0.f, 0.f};

    float cw[8];                                    // tap state of most recent ISSUE
    int row0 = 0;
    int ktap = -1;
    ub8_t stvA[16], stvB[16];                       // depth-2 in-flight gathers
    float cwA[8], cwB[8];                           // per-buffer captured weights
    ub8_t scv0, scv1;                               // conv: in-flight row registers
    float dn0 = 0.f, dn1 = 0.f, dn2 = 0.f, dn3 = 0.f; // prefetched dbuf, tap ktap+1

    auto comp_tap = [&](int k_s, float od, float oh, float ow_, float m) {
        const int kd = k_s / 9, kh = (k_s / 3) % 3, kw = k_s % 3;
        float cd = (float)(z + kd - 1) + od;
        float ch = (float)(y + kh - 1) + oh;
        float cx = (float)(xx + kw - 1) + ow_;
        float fdf = floorf(cd), fhf = floorf(ch), fwf = floorf(cx);
        float fd = cd - fdf, fh = ch - fhf, fw = cx - fwf;
        float wz0 = 1.f - fd, wz1 = fd;
        float wy0 = 1.f - fh, wy1 = fh;
        float wx0 = 1.f - fw, wx1 = fw;
        int id, ih, iw;
        if (fdf < -1.f || fdf >= 8.f)  { wz0 = 0.f; wz1 = 0.f; id = 0; } else id = (int)fdf;
        if (fhf < -1.f || fhf >= 32.f) { wy0 = 0.f; wy1 = 0.f; ih = 0; } else ih = (int)fhf;
        if (fwf < -1.f || fwf >= 32.f) { wx0 = 0.f; wx1 = 0.f; iw = 0; } else iw = (int)fwf;
        wz0 *= m; wz1 *= m;
        float w00 = wz0 * wy0, w01 = wz0 * wy1, w10 = wz1 * wy0, w11 = wz1 * wy1;
        cw[0] = w00 * wx0; cw[1] = w00 * wx1;
        cw[2] = w01 * wx0; cw[3] = w01 * wx1;
        cw[4] = w10 * wx0; cw[5] = w10 * wx1;
        cw[6] = w11 * wx0; cw[7] = w11 * wx1;
        row0 = (id + 1) * XP_SZ + (ih + 1) * XP_SY + (iw + 1);
    };
    auto pref_tap = [&](int kn) {
        dn0 = dbuf[(3 * kn + 0) * NPOS + p];
        dn1 = dbuf[(3 * kn + 1) * NPOS + p];
        dn2 = dbuf[(3 * kn + 2) * NPOS + p];
        dn3 = dbuf[(81 + kn) * NPOS + p];
    };
    // issue chunk kc_s's gathers into (sv, cwd); advances tap state if needed.
    // MUST be called in strictly increasing chunk order.
    auto issue_to = [&](ub8_t (&sv)[16], float (&cwd)[8], int kc_s) {
        const int k1 = kc_s >> 8;
        if (k1 != ktap) {
            ktap = k1;
            comp_tap(k1, dn0, dn1, dn2, dn3);
            pref_tap(k1 + 1 > 26 ? 26 : k1 + 1);
        }
#pragma unroll
        for (int j = 0; j < 8; ++j) cwd[j] = cw[j];
        const unsigned short* cb = Xp + (size_t)row0 * 256 + (kc_s & 255) + csub;
#pragma unroll
        for (int j = 0; j < 8; ++j) {
            const int roff = ((j >> 2) & 1) * XP_SZ + ((j >> 1) & 1) * XP_SY + (j & 1);
            sv[2 * j]     = *(const ub8_t*)(cb + roff * 256);
            sv[2 * j + 1] = *(const ub8_t*)(cb + roff * 256 + 8);
        }
    };
    // blend buffer -> Bs (deform)
    auto blend_write = [&](ub8_t (&sv)[16], float (&cwd)[8]) {
        float av[16];
#pragma unroll
        for (int e = 0; e < 16; ++e) av[e] = 0.f;
#pragma unroll
        for (int j = 0; j < 8; ++j) {
#pragma unroll
            for (int e = 0; e < 8; ++e) {
                av[e]     += cwd[j] * bf2f(sv[2 * j][e]);
                av[8 + e] += cwd[j] * bf2f(sv[2 * j + 1][e]);
            }
        }
        ub8_t v0, v1;
#pragma unroll
        for (int e = 0; e < 8; ++e) { v0[e] = f2bf(av[e]); v1[e] = f2bf(av[8 + e]); }
        *(ub8_t*)&Bs[wr0] = v0;
        *(ub8_t*)&Bs[wr1] = v1;
    };
    auto conv_issue = [&](int kc_s) {
        const int k_s = kc_s >> 8, c0_s = kc_s & 255;
        const int kd = k_s / 9, kh = (k_s / 3) % 3, kw = k_s % 3;
        const int row = (z + kd) * XP_SZ + (y + kh) * XP_SY + (xx + kw);
        scv0 = *(const ub8_t*)&Xp[(size_t)row * 256 + c0_s + csub];
        scv1 = *(const ub8_t*)&Xp[(size_t)row * 256 + c0_s + csub + 8];
    };
    auto load_afr = [&](bf8_t (&af)[2][4], int kc0) {
#pragma unroll
        for (int sl = 0; sl < 2; ++sl)
#pragma unroll
            for (int i = 0; i < 4; ++i)
                af[sl][i] = *(const bf8_t*)&wt[(size_t)(obw + i * 16 + r) * KTOT + kc0 + sl * 32 + q * 8];
    };
    auto do_mfma = [&](bf8_t (&af)[2][4]) {
#pragma unroll
        for (int sl = 0; sl < 2; ++sl) {
            bf8_t bfr[PWN];
#pragma unroll
            for (int ip = 0; ip < PWN; ++ip) {
                int brow = pfb + ip * 16 + r;
                bfr[ip] = *(const bf8_t*)&Bs[brow * 64 + (((sl * 4 + q) ^ (brow & 7)) << 3)];
            }
#pragma unroll
            for (int i = 0; i < 4; ++i)
#pragma unroll
                for (int ip = 0; ip < PWN; ++ip)
                    acc[i][ip] = __builtin_amdgcn_mfma_f32_16x16x32_bf16(af[sl][i], bfr[ip], acc[i][ip], 0, 0, 0);
        }
    };
    auto sync_pre = [&]() {   // ds_writes visible; vmcnt NOT drained
        asm volatile("s_waitcnt lgkmcnt(0)" ::: "memory");
        __builtin_amdgcn_s_barrier();
        __builtin_amdgcn_sched_barrier(0);
    };
    auto sync_post = [&]() {
        __builtin_amdgcn_s_barrier();
        __builtin_amdgcn_sched_barrier(0);
    };

    if constexpr (DEFORM) {
        // prologue: issue chunks 0 (->A) and 1 (->B)
        const int tap0 = kstart >> 8;
        ktap = tap0;
        comp_tap(tap0, dbuf[(3 * tap0 + 0) * NPOS + p], dbuf[(3 * tap0 + 1) * NPOS + p],
                 dbuf[(3 * tap0 + 2) * NPOS + p], dbuf[(81 + tap0) * NPOS + p]);
        pref_tap(tap0 + 1 > 26 ? 26 : tap0 + 1);
        {
#pragma unroll
            for (int j = 0; j < 8; ++j) cwA[j] = cw[j];
            const unsigned short* cb = Xp + (size_t)row0 * 256 + (kstart & 255) + csub;
#pragma unroll
            for (int j = 0; j < 8; ++j) {
                const int roff = ((j >> 2) & 1) * XP_SZ + ((j >> 1) & 1) * XP_SY + (j & 1);
                stvA[2 * j]     = *(const ub8_t*)(cb + roff * 256);
                stvA[2 * j + 1] = *(const ub8_t*)(cb + roff * 256 + 8);
            }
        }
        issue_to(stvB, cwB, kstart + 64);

        // pair-unrolled main loop: chunks 0..25, then epilogue chunk 26
        for (int c = 0; c < NCHUNK - 1; c += 2) {
            bf8_t afr[2][4];
            // even chunk c  (buffer A)
            load_afr(afr, kstart + c * 64);
            blend_write(stvA, cwA);
            issue_to(stvA, cwA, kstart + (c + 2) * 64);     // c+2 <= 26 always
            sync_pre();
            do_mfma(afr);
            sync_post();
            // odd chunk c+1 (buffer B)
            load_afr(afr, kstart + (c + 1) * 64);
            blend_write(stvB, cwB);
            if (c + 3 < NCHUNK) issue_to(stvB, cwB, kstart + (c + 3) * 64);
            sync_pre();
            do_mfma(afr);
            sync_post();
        }
        // epilogue: chunk 26 (buffer A)
        {
            bf8_t afr[2][4];
            load_afr(afr, kstart + (NCHUNK - 1) * 64);
            blend_write(stvA, cwA);
            sync_pre();
            do_mfma(afr);
            sync_post();
        }
    } else {
        conv_issue(kstart);
        for (int chunk = 0; chunk < NCHUNK; ++chunk) {
            const int kc0 = kstart + chunk * 64;
            bf8_t afr[2][4];
            load_afr(afr, kc0);
            *(ub8_t*)&Bs[wr0] = scv0;
            *(ub8_t*)&Bs[wr1] = scv1;
            if (chunk + 1 < NCHUNK) conv_issue(kc0 + 64);
            sync_pre();
            do_mfma(afr);
            sync_post();
        }
    }

    // ---- epilogue: fp32 partials; C/D map row(o)=q*4+reg, col(p)=r [R1/R2-verified] ----
    float* pp = parts + (size_t)ks * O * NPOS;
#pragma unroll
    for (int i = 0; i < 4; ++i)
#pragma unroll
        for (int ip = 0; ip < PWN; ++ip)
#pragma unroll
            for (int reg = 0; reg < 4; ++reg) {
                int o = obw + i * 16 + q * 4 + reg;
                int px = pbase + pfb + ip * 16 + r;
                pp[(size_t)o * NPOS + px] = acc[i][ip][reg];
            }
}

// ---------------- combine conv partials -> dbuf (bias + sigmoid on o>=81) ----------------
__global__ __launch_bounds__(256) void ccombine(const float* __restrict__ parts,
                                                const float* __restrict__ ob,
                                                float* __restrict__ dbuf) {
    int b = blockIdx.x;                 // 108*8
    int o = b >> 3;
    int p4 = ((b & 7) * 256 + threadIdx.x) * 4;
    float s0 = 0, s1 = 0, s2 = 0, s3 = 0;
#pragma unroll
    for (int s = 0; s < KS; ++s) {
        const float4 v = *(const float4*)&parts[((size_t)(s * 128 + o)) * NPOS + p4];
        s0 += v.x; s1 += v.y; s2 += v.z; s3 += v.w;
    }
    float bv = ob[o];
    s0 += bv; s1 += bv; s2 += bv; s3 += bv;
    if (o >= 81) {
        s0 = 1.f / (1.f + __expf(-s0));
        s1 = 1.f / (1.f + __expf(-s1));
        s2 = 1.f / (1.f + __expf(-s2));
        s3 = 1.f / (1.f + __expf(-s3));
    }
    *(float4*)&dbuf[(size_t)o * NPOS + p4] = make_float4(s0, s1, s2, s3);
}

// ---------------- combine deform partials -> relu bf16, transposed into XpB interior ----------------
__global__ __launch_bounds__(256) void dcombine_h(const float* __restrict__ parts,
                                                  const float* __restrict__ bias,
                                                  unsigned short* __restrict__ XpB) {
    __shared__ unsigned short T[64 * 66];
    int p0 = blockIdx.x * 64, o0 = blockIdx.y * 64;
    int t = threadIdx.x;
    int pl = t & 63, og = t >> 6;
#pragma unroll 4
    for (int j = 0; j < 16; ++j) {
        int ol = og * 16 + j;
        float s = 0.f;
#pragma unroll
        for (int sp = 0; sp < KS; ++sp)
            s += parts[((size_t)(sp * 256 + o0 + ol)) * NPOS + p0 + pl];
        s += bias[o0 + ol];
        T[ol * 66 + pl] = f2bf(fmaxf(s, 0.f));
    }
    __syncthreads();
    int c = t & 63, pr = t >> 6;
#pragma unroll 4
    for (int j = 0; j < 16; ++j) {
        int pl2 = j * 4 + pr;
        int pg = p0 + pl2;
        int zz = pg >> 10, yy = (pg >> 5) & 31, xv = pg & 31;
        int row = (zz + 1) * XP_SZ + (yy + 1) * XP_SY + xv + 1;
        XpB[(size_t)row * 256 + o0 + c] = T[c * 66 + pl2];
    }
}

// ---------------- final combine -> fp32 o-major output (bias only) ----------------
__global__ __launch_bounds__(256) void dcombine_out(const float* __restrict__ parts,
                                                    const float* __restrict__ bias,
                                                    float* __restrict__ out) {
    int b = blockIdx.x;                 // 256*8
    int o = b >> 3;
    int p4 = ((b & 7) * 256 + threadIdx.x) * 4;
    float s0 = 0, s1 = 0, s2 = 0, s3 = 0;
#pragma unroll
    for (int s = 0; s < KS; ++s) {
        const float4 v = *(const float4*)&parts[((size_t)(s * 256 + o)) * NPOS + p4];
        s0 += v.x; s1 += v.y; s2 += v.z; s3 += v.w;
    }
    float bv = bias[o];
    *(float4*)&out[(size_t)o * NPOS + p4] = make_float4(s0 + bv, s1 + bv, s2 + bv, s3 + bv);
}

// ---------------- host orchestration ----------------
extern "C" void kernel_launch(void* const* d_in, const int* in_sizes, int n_in,
                              void* d_out, int out_size, void* d_ws, size_t ws_size,
                              hipStream_t stream) {
    const float* x      = (const float*)d_in[0];
    const float* ow1    = (const float*)d_in[1];
    const float* ob1    = (const float*)d_in[2];
    const float* w1     = (const float*)d_in[3];
    const float* b1     = (const float*)d_in[4];
    const float* ow2    = (const float*)d_in[5];
    const float* ob2    = (const float*)d_in[6];
    const float* w2     = (const float*)d_in[7];
    const float* b2     = (const float*)d_in[8];
    const float* ow3    = (const float*)d_in[9];
    const float* ob3    = (const float*)d_in[10];
    const float* w3     = (const float*)d_in[11];
    const float* b3     = (const float*)d_in[12];
    const float* defo_w = (const float*)d_in[13];
    const float* defo_b = (const float*)d_in[14];
    const float* c3d_w  = (const float*)d_in[15];
    const float* c3d_b  = (const float*)d_in[16];
    float* out = (float*)d_out;

    // workspace carve-up (~70 MB)
    unsigned short* XpA    = (unsigned short*)d_ws;          // 2,959,360 us
    unsigned short* XpB    = XpA + (size_t)XP_ROWS * 256;    // 2,959,360 us (adjacent for zero_k)
    unsigned short* wtoff  = XpB + (size_t)XP_ROWS * 256;    // 4*128*6912
    unsigned short* wtmain = wtoff + (size_t)4 * 128 * KTOT; // 4*256*6912
    float* dbufp = (float*)(wtmain + (size_t)4 * 256 * KTOT);// 108*8192 fp32
    float* parts = dbufp + (size_t)108 * NPOS;               // KS*256*8192 fp32

    const dim3 blk(256);
    const dim3 gG(128, KS);

    zero_k<<<2890, blk, 0, stream>>>(XpA);                   // zeros XpA + XpB
    pad_x_t<<<256, blk, 0, stream>>>(x, XpA);
    wtrans_all<<<1536, blk, 0, stream>>>(ow1, ow2, ow3, defo_w, w1, w2, w3, c3d_w, wtoff, wtmain);

    const float* cbias[4] = {ob1, ob2, ob3, defo_b};
    const float* dbias[4] = {b1, b2, b3, c3d_b};

    for (int L = 0; L < 4; ++L) {
        const unsigned short* featConv = (L == 0) ? XpA : XpB;          // conv input = h_{L-1}
        const unsigned short* featDef  = (L == 3) ? XpA : featConv;     // final deform samples original x
        fgemm<false><<<gG, blk, 0, stream>>>(featConv, wtoff + (size_t)L * 128 * KTOT, nullptr, parts);
        ccombine<<<864, blk, 0, stream>>>(parts, cbias[L], dbufp);
        fgemm<true><<<gG, blk, 0, stream>>>(featDef, wtmain + (size_t)L * 256 * KTOT, dbufp, parts);
        if (L < 3) dcombine_h<<<dim3(128, 4), blk, 0, stream>>>(parts, dbias[L], XpB);
        else       dcombine_out<<<2048, blk, 0, stream>>>(parts, dbias[L], out);
    }
}

// Round 14
// 732.040 us; speedup vs baseline: 2.3306x; 2.3306x over previous
//
#include <hip/hip_runtime.h>
#include <cstdint>

// ---------------- problem constants ----------------
#define NPOS 8192              // 8*32*32 spatial positions
#define KTOT 6912              // 27 taps * 256 channels
#define XP_ROWS 11560          // 10*34*34 padded spatial rows
#define XP_SY 34
#define XP_SZ 1156             // 34*34
#define KS 4                   // K-splits
#define KSL 1728               // KTOT/KS
#define NCHUNK 27              // KSL/64

typedef float  facc_t __attribute__((ext_vector_type(4)));
typedef short  bf8_t  __attribute__((ext_vector_type(8)));   // MFMA bf16 frag (4 VGPRs)
typedef unsigned short ub8_t __attribute__((ext_vector_type(8)));

__device__ __forceinline__ unsigned short f2bf(float f) {
    unsigned u = __float_as_uint(f);
    u = (u + 0x7FFFu + ((u >> 16) & 1u)) >> 16;   // RNE
    return (unsigned short)u;
}
__device__ __forceinline__ float bf2f(unsigned short u) {
    return __uint_as_float(((unsigned)u) << 16);
}

// ---------------- zero XpA+XpB (adjacent, 2*2,959,360 us) ----------------
__global__ __launch_bounds__(256) void zero_k(unsigned short* __restrict__ dst) {
    ub8_t zz = {0,0,0,0,0,0,0,0};
    *(ub8_t*)&dst[((size_t)blockIdx.x * 256 + threadIdx.x) * 8] = zz;
}

// ---------------- pad x: fp32 c-major (256,8192) -> interior of XpA[row][256] bf16 ----------------
__global__ __launch_bounds__(256) void pad_x_t(const float* __restrict__ x,
                                               unsigned short* __restrict__ XpA) {
    __shared__ unsigned short T[256 * 33];
    int b = blockIdx.x;
    int z = b >> 5, y = b & 31;
    int t = threadIdx.x;
    int c8 = t >> 5, xv = t & 31;
#pragma unroll 4
    for (int i = 0; i < 32; ++i) {
        int c = i * 8 + c8;
        T[c * 33 + xv] = f2bf(x[c * NPOS + (z << 10) + (y << 5) + xv]);
    }
    __syncthreads();
    int rowb = ((z + 1) * XP_SZ + (y + 1) * XP_SY + 1) * 256;
#pragma unroll 4
    for (int j = 0; j < 32; ++j) {
        XpA[rowb + j * 256 + t] = T[t * 33 + j];
    }
}

// ---------------- all 8 weight transposes in one launch ----------------
__global__ __launch_bounds__(256) void wtrans_all(
    const float* __restrict__ o1, const float* __restrict__ o2,
    const float* __restrict__ o3, const float* __restrict__ o4,
    const float* __restrict__ m1, const float* __restrict__ m2,
    const float* __restrict__ m3, const float* __restrict__ m4,
    unsigned short* __restrict__ wtoff, unsigned short* __restrict__ wtmain) {
    __shared__ float T[6912];
    int b = blockIdx.x, t = threadIdx.x;
    const float* src; unsigned short* dst; int o, O;
    if (b < 512) {
        int L = b >> 7; o = b & 127; O = 108;
        src = (L == 0) ? o1 : (L == 1) ? o2 : (L == 2) ? o3 : o4;
        dst = wtoff + ((size_t)(L * 128 + o)) * KTOT;
    } else {
        int b2 = b - 512;
        int L = b2 >> 8; o = b2 & 255; O = 256;
        src = (L == 0) ? m1 : (L == 1) ? m2 : (L == 2) ? m3 : m4;
        dst = wtmain + ((size_t)(L * 256 + o)) * KTOT;
    }
    if (o < O) {
#pragma unroll 3
        for (int i = 0; i < 27; ++i) T[i * 256 + t] = src[(size_t)o * KTOT + i * 256 + t];
        __syncthreads();
#pragma unroll 3
        for (int i = 0; i < 27; ++i) {
            int kc = i * 256 + t;
            int c = kc & 255, k = kc >> 8;
            dst[kc] = f2bf(T[c * 27 + k]);
        }
    } else {
#pragma unroll 3
        for (int i = 0; i < 27; ++i) dst[i * 256 + t] = 0;
    }
}

// ---------------- fused implicit GEMM (conv or deformable), K-split partials ----------------
// R6 (T4, verified): raw s_barrier, vmcnt never drained; depth-1 register
// pipeline for staging. R8 (verified): conv pipelined, tap-lookahead.
// R13 post-mortem: depth-2 register buffers spilled (demand ~250 vs 128 cap,
// WRITE_SIZE 33->783MB). VGPR envelope is <=128.
// R14: deform TLP doubled instead — 512-thread blocks (8 waves), SAME 64p x
// 256o tile, same grid (512 blocks = 2/CU -> 16 waves/CU, 4/SIMD). Per-wave:
// 32 o-rows (IO=2), per-thread staging 8 channels (stv 8 ub8 = 32 VGPR),
// acc 32, afr 16 -> live ~110 < 128 cap of __launch_bounds__(512,4).
// Latency hiding now comes from wave interleave, not register depth.
// Conv path byte-identical to the verified 738us build.
template<bool DEFORM>
__global__ __launch_bounds__(DEFORM ? 512 : 256, DEFORM ? 4 : 2)
void fgemm(const unsigned short* __restrict__ Xp,
           const unsigned short* __restrict__ wt,   // [O][KTOT] bf16
           const float* __restrict__ dbuf,          // [108][8192] (DEFORM only)
           float* __restrict__ parts) {
    constexpr int O   = DEFORM ? 256 : 128;
    constexpr int IO  = DEFORM ? 2 : 4;             // o-frags (16 rows) per wave
    constexpr int PWN = DEFORM ? 4 : 2;             // p-frags per wave
    __shared__ unsigned short Bs[64 * 64] __attribute__((aligned(16)));

    const int t = threadIdx.x;
    const int wave = t >> 6, lane = t & 63;
    const int q = lane >> 4, r = lane & 15;

    // ---- XCD-chunked swizzle (grid (128,4) = 512 blocks) ----
    const int bid = blockIdx.x + (blockIdx.y << 7);
    const int xcd = bid & 7;
    const int idx = bid >> 3;
    const int pt  = (xcd << 4) | (idx & 15);
    const int ks  = idx >> 4;
    const int pbase = pt * 64;
    const int kstart = ks * KSL;

    const int obw = DEFORM ? (wave * 32) : ((wave >> 1) * 64);
    const int pfb = DEFORM ? 0 : ((wave & 1) * 32);

    // staging coords:
    //  deform: 512 thr -> row pl=t>>3, 8 channels at csub=(t&7)*8, granule g=t&7
    //  conv:   256 thr -> row pl=t>>2, 16 channels at csub=(t&3)*16, granules 2j,2j+1
    const int pl   = DEFORM ? (t >> 3) : (t >> 2);
    const int csub = DEFORM ? ((t & 7) * 8) : ((t & 3) * 16);
    const int p = pbase + pl;
    const int z = p >> 10, y = (p >> 5) & 31, xx = p & 31;
    const int wrD = pl * 64 + (((t & 7) ^ (pl & 7)) << 3);   // deform write slot
    const int g0 = (t & 3) * 2;                              // conv granules
    const int wr0 = pl * 64 + ((g0 ^ (pl & 7)) << 3);
    const int wr1 = pl * 64 + (((g0 + 1) ^ (pl & 7)) << 3);

    facc_t acc[IO][PWN];
#pragma unroll
    for (int i = 0; i < IO; ++i)
#pragma unroll
        for (int ip = 0; ip < PWN; ++ip) acc[i][ip] = (facc_t){0.f, 0.f, 0.f, 0.f};

    float cw[8];
    int row0 = 0;
    int ktap = -1;
    ub8_t stv[8];                                   // deform: 8 corners x 8ch (32 VGPR)
    ub8_t scv0, scv1;                               // conv: in-flight row registers
    float dn0 = 0.f, dn1 = 0.f, dn2 = 0.f, dn3 = 0.f; // prefetched dbuf, tap ktap+1

    auto comp_tap = [&](int k_s, float od, float oh, float ow_, float m) {
        const int kd = k_s / 9, kh = (k_s / 3) % 3, kw = k_s % 3;
        float cd = (float)(z + kd - 1) + od;
        float ch = (float)(y + kh - 1) + oh;
        float cx = (float)(xx + kw - 1) + ow_;
        float fdf = floorf(cd), fhf = floorf(ch), fwf = floorf(cx);
        float fd = cd - fdf, fh = ch - fhf, fw = cx - fwf;
        float wz0 = 1.f - fd, wz1 = fd;
        float wy0 = 1.f - fh, wy1 = fh;
        float wx0 = 1.f - fw, wx1 = fw;
        int id, ih, iw;
        if (fdf < -1.f || fdf >= 8.f)  { wz0 = 0.f; wz1 = 0.f; id = 0; } else id = (int)fdf;
        if (fhf < -1.f || fhf >= 32.f) { wy0 = 0.f; wy1 = 0.f; ih = 0; } else ih = (int)fhf;
        if (fwf < -1.f || fwf >= 32.f) { wx0 = 0.f; wx1 = 0.f; iw = 0; } else iw = (int)fwf;
        wz0 *= m; wz1 *= m;
        float w00 = wz0 * wy0, w01 = wz0 * wy1, w10 = wz1 * wy0, w11 = wz1 * wy1;
        cw[0] = w00 * wx0; cw[1] = w00 * wx1;
        cw[2] = w01 * wx0; cw[3] = w01 * wx1;
        cw[4] = w10 * wx0; cw[5] = w10 * wx1;
        cw[6] = w11 * wx0; cw[7] = w11 * wx1;
        row0 = (id + 1) * XP_SZ + (ih + 1) * XP_SY + (iw + 1);
    };
    auto pref_tap = [&](int kn) {
        dn0 = dbuf[(3 * kn + 0) * NPOS + p];
        dn1 = dbuf[(3 * kn + 1) * NPOS + p];
        dn2 = dbuf[(3 * kn + 2) * NPOS + p];
        dn3 = dbuf[(81 + kn) * NPOS + p];
    };
    // issue the 8 corner gathers (8 channels each) for channel base c0_s
    auto issue_gathers = [&](int c0_s) {
        const unsigned short* cb = Xp + (size_t)row0 * 256 + c0_s + csub;
#pragma unroll
        for (int j = 0; j < 8; ++j) {
            const int roff = ((j >> 2) & 1) * XP_SZ + ((j >> 1) & 1) * XP_SY + (j & 1);
            stv[j] = *(const ub8_t*)(cb + roff * 256);
        }
    };
    auto conv_issue = [&](int kc_s) {
        const int k_s = kc_s >> 8, c0_s = kc_s & 255;
        const int kd = k_s / 9, kh = (k_s / 3) % 3, kw = k_s % 3;
        const int row = (z + kd) * XP_SZ + (y + kh) * XP_SY + (xx + kw);
        scv0 = *(const ub8_t*)&Xp[(size_t)row * 256 + c0_s + csub];
        scv1 = *(const ub8_t*)&Xp[(size_t)row * 256 + c0_s + csub + 8];
    };

    if (DEFORM) {
        ktap = kstart >> 8;
        comp_tap(ktap, dbuf[(3 * ktap + 0) * NPOS + p], dbuf[(3 * ktap + 1) * NPOS + p],
                 dbuf[(3 * ktap + 2) * NPOS + p], dbuf[(81 + ktap) * NPOS + p]);
        pref_tap(ktap + 1 > 26 ? 26 : ktap + 1);
        issue_gathers(kstart & 255);
    } else {
        conv_issue(kstart);
    }

    for (int chunk = 0; chunk < NCHUNK; ++chunk) {
        const int kc0 = kstart + chunk * 64;

        // ---- A-fragments (L2-resident weights) ----
        bf8_t afr[2][IO];
#pragma unroll
        for (int sl = 0; sl < 2; ++sl)
#pragma unroll
            for (int i = 0; i < IO; ++i)
                afr[sl][i] = *(const bf8_t*)&wt[(size_t)(obw + i * 16 + r) * KTOT + kc0 + sl * 32 + q * 8];

        // ---- B staging ----
        if (DEFORM) {
            // blend this chunk's prefetched gathers (8 corners x 8 channels)
            float av[8];
#pragma unroll
            for (int e = 0; e < 8; ++e) av[e] = 0.f;
#pragma unroll
            for (int j = 0; j < 8; ++j) {
#pragma unroll
                for (int e = 0; e < 8; ++e)
                    av[e] += cw[j] * bf2f(stv[j][e]);
            }
            ub8_t v0;
#pragma unroll
            for (int e = 0; e < 8; ++e) v0[e] = f2bf(av[e]);
            // issue next chunk's gathers (stay in flight across barriers/MFMA)
            if (chunk + 1 < NCHUNK) {
                const int kc1 = kc0 + 64;
                const int k1 = kc1 >> 8;
                if (k1 != ktap) {
                    ktap = k1;
                    comp_tap(k1, dn0, dn1, dn2, dn3);
                    pref_tap(k1 + 1 > 26 ? 26 : k1 + 1);
                }
                issue_gathers(kc1 & 255);
            }
            *(ub8_t*)&Bs[wrD] = v0;
        } else {
            *(ub8_t*)&Bs[wr0] = scv0;
            *(ub8_t*)&Bs[wr1] = scv1;
            if (chunk + 1 < NCHUNK) conv_issue(kc0 + 64);
        }

        // ---- barrier WITHOUT vmcnt drain ----
        asm volatile("s_waitcnt lgkmcnt(0)" ::: "memory");
        __builtin_amdgcn_s_barrier();
        __builtin_amdgcn_sched_barrier(0);

        // ---- MFMA ----
#pragma unroll
        for (int sl = 0; sl < 2; ++sl) {
            bf8_t bfr[PWN];
#pragma unroll
            for (int ip = 0; ip < PWN; ++ip) {
                int brow = pfb + ip * 16 + r;
                bfr[ip] = *(const bf8_t*)&Bs[brow * 64 + (((sl * 4 + q) ^ (brow & 7)) << 3)];
            }
#pragma unroll
            for (int i = 0; i < IO; ++i)
#pragma unroll
                for (int ip = 0; ip < PWN; ++ip)
                    acc[i][ip] = __builtin_amdgcn_mfma_f32_16x16x32_bf16(afr[sl][i], bfr[ip], acc[i][ip], 0, 0, 0);
        }

        __builtin_amdgcn_s_barrier();
        __builtin_amdgcn_sched_barrier(0);
    }

    // ---- epilogue: fp32 partials; C/D map row(o)=q*4+reg, col(p)=r [R1/R2-verified] ----
    float* pp = parts + (size_t)ks * O * NPOS;
#pragma unroll
    for (int i = 0; i < IO; ++i)
#pragma unroll
        for (int ip = 0; ip < PWN; ++ip)
#pragma unroll
            for (int reg = 0; reg < 4; ++reg) {
                int o = obw + i * 16 + q * 4 + reg;
                int px = pbase + pfb + ip * 16 + r;
                pp[(size_t)o * NPOS + px] = acc[i][ip][reg];
            }
}

// ---------------- combine conv partials -> dbuf (bias + sigmoid on o>=81) ----------------
__global__ __launch_bounds__(256) void ccombine(const float* __restrict__ parts,
                                                const float* __restrict__ ob,
                                                float* __restrict__ dbuf) {
    int b = blockIdx.x;                 // 108*8
    int o = b >> 3;
    int p4 = ((b & 7) * 256 + threadIdx.x) * 4;
    float s0 = 0, s1 = 0, s2 = 0, s3 = 0;
#pragma unroll
    for (int s = 0; s < KS; ++s) {
        const float4 v = *(const float4*)&parts[((size_t)(s * 128 + o)) * NPOS + p4];
        s0 += v.x; s1 += v.y; s2 += v.z; s3 += v.w;
    }
    float bv = ob[o];
    s0 += bv; s1 += bv; s2 += bv; s3 += bv;
    if (o >= 81) {
        s0 = 1.f / (1.f + __expf(-s0));
        s1 = 1.f / (1.f + __expf(-s1));
        s2 = 1.f / (1.f + __expf(-s2));
        s3 = 1.f / (1.f + __expf(-s3));
    }
    *(float4*)&dbuf[(size_t)o * NPOS + p4] = make_float4(s0, s1, s2, s3);
}

// ---------------- combine deform partials -> relu bf16, transposed into XpB interior ----------------
__global__ __launch_bounds__(256) void dcombine_h(const float* __restrict__ parts,
                                                  const float* __restrict__ bias,
                                                  unsigned short* __restrict__ XpB) {
    __shared__ unsigned short T[64 * 66];
    int p0 = blockIdx.x * 64, o0 = blockIdx.y * 64;
    int t = threadIdx.x;
    int pl = t & 63, og = t >> 6;
#pragma unroll 4
    for (int j = 0; j < 16; ++j) {
        int ol = og * 16 + j;
        float s = 0.f;
#pragma unroll
        for (int sp = 0; sp < KS; ++sp)
            s += parts[((size_t)(sp * 256 + o0 + ol)) * NPOS + p0 + pl];
        s += bias[o0 + ol];
        T[ol * 66 + pl] = f2bf(fmaxf(s, 0.f));
    }
    __syncthreads();
    int c = t & 63, pr = t >> 6;
#pragma unroll 4
    for (int j = 0; j < 16; ++j) {
        int pl2 = j * 4 + pr;
        int pg = p0 + pl2;
        int zz = pg >> 10, yy = (pg >> 5) & 31, xv = pg & 31;
        int row = (zz + 1) * XP_SZ + (yy + 1) * XP_SY + xv + 1;
        XpB[(size_t)row * 256 + o0 + c] = T[c * 66 + pl2];
    }
}

// ---------------- final combine -> fp32 o-major output (bias only) ----------------
__global__ __launch_bounds__(256) void dcombine_out(const float* __restrict__ parts,
                                                    const float* __restrict__ bias,
                                                    float* __restrict__ out) {
    int b = blockIdx.x;                 // 256*8
    int o = b >> 3;
    int p4 = ((b & 7) * 256 + threadIdx.x) * 4;
    float s0 = 0, s1 = 0, s2 = 0, s3 = 0;
#pragma unroll
    for (int s = 0; s < KS; ++s) {
        const float4 v = *(const float4*)&parts[((size_t)(s * 256 + o)) * NPOS + p4];
        s0 += v.x; s1 += v.y; s2 += v.z; s3 += v.w;
    }
    float bv = bias[o];
    *(float4*)&out[(size_t)o * NPOS + p4] = make_float4(s0 + bv, s1 + bv, s2 + bv, s3 + bv);
}

// ---------------- host orchestration ----------------
extern "C" void kernel_launch(void* const* d_in, const int* in_sizes, int n_in,
                              void* d_out, int out_size, void* d_ws, size_t ws_size,
                              hipStream_t stream) {
    const float* x      = (const float*)d_in[0];
    const float* ow1    = (const float*)d_in[1];
    const float* ob1    = (const float*)d_in[2];
    const float* w1     = (const float*)d_in[3];
    const float* b1     = (const float*)d_in[4];
    const float* ow2    = (const float*)d_in[5];
    const float* ob2    = (const float*)d_in[6];
    const float* w2     = (const float*)d_in[7];
    const float* b2     = (const float*)d_in[8];
    const float* ow3    = (const float*)d_in[9];
    const float* ob3    = (const float*)d_in[10];
    const float* w3     = (const float*)d_in[11];
    const float* b3     = (const float*)d_in[12];
    const float* defo_w = (const float*)d_in[13];
    const float* defo_b = (const float*)d_in[14];
    const float* c3d_w  = (const float*)d_in[15];
    const float* c3d_b  = (const float*)d_in[16];
    float* out = (float*)d_out;

    // workspace carve-up (~70 MB)
    unsigned short* XpA    = (unsigned short*)d_ws;          // 2,959,360 us
    unsigned short* XpB    = XpA + (size_t)XP_ROWS * 256;    // 2,959,360 us (adjacent for zero_k)
    unsigned short* wtoff  = XpB + (size_t)XP_ROWS * 256;    // 4*128*6912
    unsigned short* wtmain = wtoff + (size_t)4 * 128 * KTOT; // 4*256*6912
    float* dbufp = (float*)(wtmain + (size_t)4 * 256 * KTOT);// 108*8192 fp32
    float* parts = dbufp + (size_t)108 * NPOS;               // KS*256*8192 fp32

    const dim3 blk(256);
    const dim3 blkD(512);
    const dim3 gG(128, KS);

    zero_k<<<2890, blk, 0, stream>>>(XpA);                   // zeros XpA + XpB
    pad_x_t<<<256, blk, 0, stream>>>(x, XpA);
    wtrans_all<<<1536, blk, 0, stream>>>(ow1, ow2, ow3, defo_w, w1, w2, w3, c3d_w, wtoff, wtmain);

    const float* cbias[4] = {ob1, ob2, ob3, defo_b};
    const float* dbias[4] = {b1, b2, b3, c3d_b};

    for (int L = 0; L < 4; ++L) {
        const unsigned short* featConv = (L == 0) ? XpA : XpB;          // conv input = h_{L-1}
        const unsigned short* featDef  = (L == 3) ? XpA : featConv;     // final deform samples original x
        fgemm<false><<<gG, blk, 0, stream>>>(featConv, wtoff + (size_t)L * 128 * KTOT, nullptr, parts);
        ccombine<<<864, blk, 0, stream>>>(parts, cbias[L], dbufp);
        fgemm<true><<<gG, blkD, 0, stream>>>(featDef, wtmain + (size_t)L * 256 * KTOT, dbufp, parts);
        if (L < 3) dcombine_h<<<dim3(128, 4), blk, 0, stream>>>(parts, dbias[L], XpB);
        else       dcombine_out<<<2048, blk, 0, stream>>>(parts, dbias[L], out);
    }
}